// Round 1
// baseline (84.161 us; speedup 1.0000x reference)
//
#include <hip/hip_runtime.h>

// Problem constants (from setup_inputs): H=1536, W=2048, k=3, stride=4.
// k=3 is structural (window unrolled); stride read from d_in[2] at runtime.
constexpr int H = 1536;
constexpr int W = 2048;

__global__ __launch_bounds__(256)
void counting_post_kernel(const float* __restrict__ in,
                          const int* __restrict__ stride_p,
                          float* __restrict__ out) {
    const int W4 = W / 4;
    const int tid = blockIdx.x * blockDim.x + threadIdx.x;
    const int r  = tid / W4;
    const int c0 = (tid - r * W4) * 4;
    if (r >= H) return;

    const float s = (float)(*stride_p);

    // Load 3 rows x 6 cols (c0-1 .. c0+4), relu'd, zero-padded.
    float v[3][6];
#pragma unroll
    for (int dr = 0; dr < 3; ++dr) {
        const int rr = r + dr - 1;
        if (rr < 0 || rr >= H) {
#pragma unroll
            for (int j = 0; j < 6; ++j) v[dr][j] = 0.f;
        } else {
            const float* row = in + (size_t)rr * W + c0;
            const float4 mid = *reinterpret_cast<const float4*>(row);
            v[dr][1] = fmaxf(mid.x, 0.f);
            v[dr][2] = fmaxf(mid.y, 0.f);
            v[dr][3] = fmaxf(mid.z, 0.f);
            v[dr][4] = fmaxf(mid.w, 0.f);
            v[dr][0] = (c0 > 0)     ? fmaxf(row[-1], 0.f) : 0.f;
            v[dr][5] = (c0 + 4 < W) ? fmaxf(row[4],  0.f) : 0.f;
        }
    }

    float f_o[4], cw_o[4], ch_o[4];
#pragma unroll
    for (int p = 0; p < 4; ++p) {
        const float w00 = v[0][p], w01 = v[0][p+1], w02 = v[0][p+2];
        const float w10 = v[1][p], w11 = v[1][p+1], w12 = v[1][p+2];
        const float w20 = v[2][p], w21 = v[2][p+1], w22 = v[2][p+2];

        const float sum = w00 + w01 + w02 + w10 + w11 + w12 + w20 + w21 + w22;

        // argmax (first occurrence) over row-major taps == center(4):
        // strictly greater than earlier taps, >= later taps.
        const bool mask = (w11 > w00) && (w11 > w01) && (w11 > w02) && (w11 > w10)
                       && (w11 >= w12) && (w11 >= w20) && (w11 >= w21) && (w11 >= w22);
        f_o[p] = (sum > 0.5f && mask) ? 1.f : 0.f;

        const float denom = fmaxf(sum, 1e-12f);
        const float inv   = 1.f / denom;

        const int c = c0 + p;
        // Out-of-bounds taps have v==0, so raw coordinates are safe.
        const float wh = (float)(r - 1) * (w00 + w01 + w02)
                       + (float)(r    ) * (w10 + w11 + w12)
                       + (float)(r + 1) * (w20 + w21 + w22);
        const float ww = (float)(c - 1) * (w00 + w10 + w20)
                       + (float)(c    ) * (w01 + w11 + w21)
                       + (float)(c + 1) * (w02 + w12 + w22);

        cw_o[p] = s * (ww * inv) + 0.5f;
        ch_o[p] = s * (wh * inv) + 0.5f;
    }

    const size_t base  = (size_t)r * W + c0;
    const size_t plane = (size_t)H * W;
    *reinterpret_cast<float4*>(out + base)             = make_float4(f_o[0],  f_o[1],  f_o[2],  f_o[3]);
    *reinterpret_cast<float4*>(out + plane + base)     = make_float4(cw_o[0], cw_o[1], cw_o[2], cw_o[3]);
    *reinterpret_cast<float4*>(out + 2 * plane + base) = make_float4(ch_o[0], ch_o[1], ch_o[2], ch_o[3]);
}

extern "C" void kernel_launch(void* const* d_in, const int* in_sizes, int n_in,
                              void* d_out, int out_size, void* d_ws, size_t ws_size,
                              hipStream_t stream) {
    const float* in      = (const float*)d_in[0];
    const int*   stride  = (const int*)d_in[2];   // d_in[1] = loc_kernel_size (=3, structural)
    float*       out     = (float*)d_out;

    const int threads = 256;
    const int total   = H * (W / 4);              // one thread per 4 pixels
    const int blocks  = (total + threads - 1) / threads;
    counting_post_kernel<<<blocks, threads, 0, stream>>>(in, stride, out);
}